// Round 1
// baseline (2801.142 us; speedup 1.0000x reference)
//
#include <hip/hip_runtime.h>

#define NUM_USER  200000
#define NUM_GROUP 50000
#define NN        (NUM_USER + NUM_GROUP)   // 250000
#define E_EDGES   4000000
#define D         64
#define B         8192

// ---------------------------------------------------------------------------
// emb0 = concat(user_table, group_table), vectorized float4
// ---------------------------------------------------------------------------
__global__ void init_emb(const float* __restrict__ ut,
                         const float* __restrict__ gt,
                         float* __restrict__ emb) {
    const long long total = (long long)NN * D / 4;          // 4M float4
    const long long userElems = (long long)NUM_USER * D / 4;
    long long i = (long long)blockIdx.x * blockDim.x + threadIdx.x;
    if (i >= total) return;
    float4 v;
    if (i < userElems) v = ((const float4*)ut)[i];
    else               v = ((const float4*)gt)[i - userElems];
    ((float4*)emb)[i] = v;
}

// ---------------------------------------------------------------------------
// SpMM scatter: y[rows[e]] += vals[e] * x[cols[e]]   (one wave per edge,
// lane = dimension; coalesced 256B read + coalesced 256B atomic add)
// ---------------------------------------------------------------------------
__global__ void __launch_bounds__(256)
spmm_atomic(const int*   __restrict__ rows,
            const int*   __restrict__ cols,
            const float* __restrict__ vals,
            const float* __restrict__ x,
            float*       __restrict__ y) {
    int edge = blockIdx.x * 4 + (threadIdx.x >> 6);   // 4 waves / block
    int lane = threadIdx.x & 63;
    if (edge >= E_EDGES) return;
    int   r = rows[edge];
    int   c = cols[edge];
    float v = vals[edge];
    float xv = x[(long long)c * D + lane];
    atomicAdd(&y[(long long)r * D + lane], v * xv);
}

// ---------------------------------------------------------------------------
// Output init: raw table gathers (outputs 3..5) and the level-0 contribution
// (0.25 * emb0[idx]) into outputs 0..2.
// ---------------------------------------------------------------------------
__global__ void gather_init(const float* __restrict__ ut,
                            const float* __restrict__ gt,
                            const int*   __restrict__ ui,
                            const int*   __restrict__ pg,
                            const int*   __restrict__ ng,
                            float*       __restrict__ out) {
    int i = blockIdx.x * blockDim.x + threadIdx.x;    // B*D threads
    if (i >= B * D) return;
    int b = i >> 6, d = i & 63;
    float u = ut[(long long)ui[b] * D + d];
    float p = gt[(long long)pg[b] * D + d];
    float n = gt[(long long)ng[b] * D + d];
    const int S = B * D;
    out[0 * S + i] = 0.25f * u;
    out[1 * S + i] = 0.25f * p;
    out[2 * S + i] = 0.25f * n;
    out[3 * S + i] = u;
    out[4 * S + i] = p;
    out[5 * S + i] = n;
}

// ---------------------------------------------------------------------------
// Per-level accumulation of 0.25 * emb_l at the gathered rows into outputs 0..2
// ---------------------------------------------------------------------------
__global__ void gather_acc(const float* __restrict__ emb,
                           const int*   __restrict__ ui,
                           const int*   __restrict__ pg,
                           const int*   __restrict__ ng,
                           float*       __restrict__ out) {
    int i = blockIdx.x * blockDim.x + threadIdx.x;    // B*D threads
    if (i >= B * D) return;
    int b = i >> 6, d = i & 63;
    const int S = B * D;
    out[0 * S + i] += 0.25f * emb[(long long)ui[b] * D + d];
    out[1 * S + i] += 0.25f * emb[((long long)NUM_USER + pg[b]) * D + d];
    out[2 * S + i] += 0.25f * emb[((long long)NUM_USER + ng[b]) * D + d];
}

// ---------------------------------------------------------------------------
extern "C" void kernel_launch(void* const* d_in, const int* in_sizes, int n_in,
                              void* d_out, int out_size, void* d_ws, size_t ws_size,
                              hipStream_t stream) {
    const float* ut   = (const float*)d_in[0];
    const float* gt   = (const float*)d_in[1];
    const float* vals = (const float*)d_in[2];
    const int*   rows = (const int*)d_in[3];
    const int*   cols = (const int*)d_in[4];
    const int*   ui   = (const int*)d_in[5];
    const int*   pg   = (const int*)d_in[6];
    const int*   ng   = (const int*)d_in[7];
    float* out = (float*)d_out;

    float* emb_a = (float*)d_ws;                       // N*D fp32 = 64 MB
    float* emb_b = emb_a + (size_t)NN * D;             // second 64 MB

    const size_t embBytes = (size_t)NN * D * sizeof(float);

    // emb0 = concat(tables)
    {
        long long total = (long long)NN * D / 4;
        int blocks = (int)((total + 255) / 256);
        init_emb<<<blocks, 256, 0, stream>>>(ut, gt, emb_a);
    }
    // outputs 3..5 + level-0 contribution to 0..2
    gather_init<<<(B * D + 255) / 256, 256, 0, stream>>>(ut, gt, ui, pg, ng, out);

    float* cur = emb_a;
    float* nxt = emb_b;
    for (int l = 0; l < 3; ++l) {
        hipMemsetAsync(nxt, 0, embBytes, stream);
        spmm_atomic<<<(E_EDGES + 3) / 4, 256, 0, stream>>>(rows, cols, vals, cur, nxt);
        gather_acc<<<(B * D + 255) / 256, 256, 0, stream>>>(nxt, ui, pg, ng, out);
        float* t = cur; cur = nxt; nxt = t;
    }
}

// Round 2
// 1574.657 us; speedup vs baseline: 1.7789x; 1.7789x over previous
//
#include <hip/hip_runtime.h>

#define NUM_USER  200000
#define NUM_GROUP 50000
#define NN        (NUM_USER + NUM_GROUP)   // 250000
#define E_EDGES   4000000
#define D         64
#define B         8192

// ---------------------------------------------------------------------------
// CSR build step 1: histogram of destination rows
// ---------------------------------------------------------------------------
__global__ void __launch_bounds__(256)
hist_kernel(const int* __restrict__ rows, int* __restrict__ counts) {
    int e = blockIdx.x * blockDim.x + threadIdx.x;
    if (e >= E_EDGES) return;
    atomicAdd(&counts[rows[e]], 1);
}

// ---------------------------------------------------------------------------
// CSR build step 2: exclusive scan of 250K counts, single workgroup.
// Writes row_ptr[NN+1] and a scratch cursor copy for the scatter pass.
// ---------------------------------------------------------------------------
#define SCAN_THREADS 1024
__global__ void __launch_bounds__(SCAN_THREADS)
scan_kernel(const int* __restrict__ counts,
            int* __restrict__ row_ptr,
            int* __restrict__ cursor) {
    __shared__ int sums[SCAN_THREADS];
    const int t = threadIdx.x;
    const int items = (NN + SCAN_THREADS - 1) / SCAN_THREADS;   // 245
    const int begin = t * items;
    const int endi  = begin + items < NN ? begin + items : NN;
    int s = 0;
    for (int i = begin; i < endi; ++i) s += counts[i];
    sums[t] = s;
    __syncthreads();
    // inclusive Hillis-Steele scan over per-thread sums
    for (int off = 1; off < SCAN_THREADS; off <<= 1) {
        int v = (t >= off) ? sums[t - off] : 0;
        __syncthreads();
        sums[t] += v;
        __syncthreads();
    }
    int run = (t == 0) ? 0 : sums[t - 1];                       // exclusive prefix
    for (int i = begin; i < endi; ++i) {
        row_ptr[i] = run;
        cursor[i]  = run;
        run += counts[i];
    }
    if (t == SCAN_THREADS - 1) row_ptr[NN] = run;
}

// ---------------------------------------------------------------------------
// CSR build step 3: scatter (col,val) pairs into row-sorted order
// ---------------------------------------------------------------------------
__global__ void __launch_bounds__(256)
scatter_kernel(const int*   __restrict__ rows,
               const int*   __restrict__ cols,
               const float* __restrict__ vals,
               int*         __restrict__ cursor,
               int2*        __restrict__ pairs) {
    int e = blockIdx.x * blockDim.x + threadIdx.x;
    if (e >= E_EDGES) return;
    int r = rows[e];
    int pos = atomicAdd(&cursor[r], 1);
    pairs[pos] = make_int2(cols[e], __float_as_int(vals[e]));
}

// ---------------------------------------------------------------------------
// Pull-mode SpMM: one wave per destination row, lane = dim.
// y[row][lane] = sum over CSR edges of val * x[col][lane].
// FIRST level reads directly from the concat(user_table, group_table) view.
// ---------------------------------------------------------------------------
template <bool FIRST>
__global__ void __launch_bounds__(256)
spmm_pull(const int*  __restrict__ row_ptr,
          const int2* __restrict__ pairs,
          const float* __restrict__ ut,
          const float* __restrict__ gt,
          const float* __restrict__ x,
          float*       __restrict__ y) {
    int row  = blockIdx.x * 4 + (threadIdx.x >> 6);   // 4 waves / block
    int lane = threadIdx.x & 63;
    if (row >= NN) return;
    int start = row_ptr[row];
    int end   = row_ptr[row + 1];

    auto loadx = [&](int c) -> float {
        if (FIRST) {
            return (c < NUM_USER) ? ut[(size_t)c * D + lane]
                                  : gt[(size_t)(c - NUM_USER) * D + lane];
        } else {
            return x[(size_t)c * D + lane];
        }
    };

    float acc = 0.f;
    int e = start;
    for (; e + 4 <= end; e += 4) {
        int2 p0 = pairs[e + 0];
        int2 p1 = pairs[e + 1];
        int2 p2 = pairs[e + 2];
        int2 p3 = pairs[e + 3];
        float x0 = loadx(p0.x);
        float x1 = loadx(p1.x);
        float x2 = loadx(p2.x);
        float x3 = loadx(p3.x);
        acc += __int_as_float(p0.y) * x0;
        acc += __int_as_float(p1.y) * x1;
        acc += __int_as_float(p2.y) * x2;
        acc += __int_as_float(p3.y) * x3;
    }
    for (; e < end; ++e) {
        int2 p = pairs[e];
        acc += __int_as_float(p.y) * loadx(p.x);
    }
    y[(size_t)row * D + lane] = acc;
}

// ---------------------------------------------------------------------------
// Output init: raw table gathers (outputs 3..5) and the level-0 contribution
// ---------------------------------------------------------------------------
__global__ void gather_init(const float* __restrict__ ut,
                            const float* __restrict__ gt,
                            const int*   __restrict__ ui,
                            const int*   __restrict__ pg,
                            const int*   __restrict__ ng,
                            float*       __restrict__ out) {
    int i = blockIdx.x * blockDim.x + threadIdx.x;    // B*D threads
    if (i >= B * D) return;
    int b = i >> 6, d = i & 63;
    float u = ut[(size_t)ui[b] * D + d];
    float p = gt[(size_t)pg[b] * D + d];
    float n = gt[(size_t)ng[b] * D + d];
    const int S = B * D;
    out[0 * S + i] = 0.25f * u;
    out[1 * S + i] = 0.25f * p;
    out[2 * S + i] = 0.25f * n;
    out[3 * S + i] = u;
    out[4 * S + i] = p;
    out[5 * S + i] = n;
}

// ---------------------------------------------------------------------------
// Per-level accumulation of 0.25 * emb_l at the gathered rows
// ---------------------------------------------------------------------------
__global__ void gather_acc(const float* __restrict__ emb,
                           const int*   __restrict__ ui,
                           const int*   __restrict__ pg,
                           const int*   __restrict__ ng,
                           float*       __restrict__ out) {
    int i = blockIdx.x * blockDim.x + threadIdx.x;    // B*D threads
    if (i >= B * D) return;
    int b = i >> 6, d = i & 63;
    const int S = B * D;
    out[0 * S + i] += 0.25f * emb[(size_t)ui[b] * D + d];
    out[1 * S + i] += 0.25f * emb[((size_t)NUM_USER + pg[b]) * D + d];
    out[2 * S + i] += 0.25f * emb[((size_t)NUM_USER + ng[b]) * D + d];
}

// ---------------------------------------------------------------------------
extern "C" void kernel_launch(void* const* d_in, const int* in_sizes, int n_in,
                              void* d_out, int out_size, void* d_ws, size_t ws_size,
                              hipStream_t stream) {
    const float* ut   = (const float*)d_in[0];
    const float* gt   = (const float*)d_in[1];
    const float* vals = (const float*)d_in[2];
    const int*   rows = (const int*)d_in[3];
    const int*   cols = (const int*)d_in[4];
    const int*   ui   = (const int*)d_in[5];
    const int*   pg   = (const int*)d_in[6];
    const int*   ng   = (const int*)d_in[7];
    float* out = (float*)d_out;

    // --- workspace layout ---
    char* ws = (char*)d_ws;
    float* emb_a  = (float*)ws;                        ws += (size_t)NN * D * sizeof(float);  // 64 MB
    float* emb_b  = (float*)ws;                        ws += (size_t)NN * D * sizeof(float);  // 64 MB
    int2*  pairs  = (int2*)ws;                         ws += (size_t)E_EDGES * sizeof(int2);  // 32 MB
    int*   row_ptr = (int*)ws;                         ws += (size_t)(NN + 1) * sizeof(int);
    int*   cursor  = (int*)ws;                         ws += (size_t)NN * sizeof(int);
    int*   counts  = (int*)ws;                         ws += (size_t)NN * sizeof(int);

    // --- CSR build (once per call; reused for all 3 levels) ---
    hipMemsetAsync(counts, 0, (size_t)NN * sizeof(int), stream);
    hist_kernel<<<(E_EDGES + 255) / 256, 256, 0, stream>>>(rows, counts);
    scan_kernel<<<1, SCAN_THREADS, 0, stream>>>(counts, row_ptr, cursor);
    scatter_kernel<<<(E_EDGES + 255) / 256, 256, 0, stream>>>(rows, cols, vals, cursor, pairs);

    // --- outputs 3..5 + level-0 contribution ---
    gather_init<<<(B * D + 255) / 256, 256, 0, stream>>>(ut, gt, ui, pg, ng, out);

    // --- 3 propagation levels, pull mode ---
    const int spmmBlocks = (NN + 3) / 4;   // 4 rows (waves) per 256-thread block
    spmm_pull<true><<<spmmBlocks, 256, 0, stream>>>(row_ptr, pairs, ut, gt, nullptr, emb_a);
    gather_acc<<<(B * D + 255) / 256, 256, 0, stream>>>(emb_a, ui, pg, ng, out);

    spmm_pull<false><<<spmmBlocks, 256, 0, stream>>>(row_ptr, pairs, ut, gt, emb_a, emb_b);
    gather_acc<<<(B * D + 255) / 256, 256, 0, stream>>>(emb_b, ui, pg, ng, out);

    spmm_pull<false><<<spmmBlocks, 256, 0, stream>>>(row_ptr, pairs, ut, gt, emb_b, emb_a);
    gather_acc<<<(B * D + 255) / 256, 256, 0, stream>>>(emb_a, ui, pg, ng, out);
}

// Round 3
// 1035.510 us; speedup vs baseline: 2.7051x; 1.5207x over previous
//
#include <hip/hip_runtime.h>

#define NUM_USER  200000
#define NUM_GROUP 50000
#define NN        (NUM_USER + NUM_GROUP)   // 250000
#define E_EDGES   4000000
#define D         64
#define B         8192

#define SCAN_CHUNK   1024                         // counts per block
#define SCAN_BLOCKS  ((NN + SCAN_CHUNK - 1) / SCAN_CHUNK)   // 245

// ---------------------------------------------------------------------------
// CSR build step 1: histogram of destination rows
// ---------------------------------------------------------------------------
__global__ void __launch_bounds__(256)
hist_kernel(const int* __restrict__ rows, int* __restrict__ counts) {
    int e = blockIdx.x * blockDim.x + threadIdx.x;
    if (e >= E_EDGES) return;
    atomicAdd(&counts[rows[e]], 1);
}

// ---------------------------------------------------------------------------
// Scan pass A: per-block sums of 1024 counts each
// ---------------------------------------------------------------------------
__global__ void __launch_bounds__(256)
scan_blocksums(const int* __restrict__ counts, int* __restrict__ blockSums) {
    __shared__ int red[256];
    const int t = threadIdx.x;
    const int base = blockIdx.x * SCAN_CHUNK + t * 4;
    int s = 0;
    #pragma unroll
    for (int k = 0; k < 4; ++k) {
        int i = base + k;
        if (i < NN) s += counts[i];
    }
    red[t] = s;
    __syncthreads();
    for (int off = 128; off > 0; off >>= 1) {
        if (t < off) red[t] += red[t + off];
        __syncthreads();
    }
    if (t == 0) blockSums[blockIdx.x] = red[0];
}

// ---------------------------------------------------------------------------
// Scan pass B: exclusive scan of the 245 block sums (single small block)
// ---------------------------------------------------------------------------
__global__ void __launch_bounds__(256)
scan_offsets(const int* __restrict__ blockSums,
             int* __restrict__ blockOffs,
             int* __restrict__ row_ptr) {
    __shared__ int s[256];
    const int t = threadIdx.x;
    int v = (t < SCAN_BLOCKS) ? blockSums[t] : 0;
    s[t] = v;
    __syncthreads();
    for (int off = 1; off < 256; off <<= 1) {
        int u = (t >= off) ? s[t - off] : 0;
        __syncthreads();
        s[t] += u;
        __syncthreads();
    }
    if (t < SCAN_BLOCKS) blockOffs[t] = s[t] - v;   // exclusive
    if (t == 255) row_ptr[NN] = s[255];             // grand total = E
}

// ---------------------------------------------------------------------------
// Scan pass C: intra-block exclusive scan + global offset -> row_ptr, cursor
// ---------------------------------------------------------------------------
__global__ void __launch_bounds__(256)
scan_final(const int* __restrict__ counts,
           const int* __restrict__ blockOffs,
           int* __restrict__ row_ptr,
           int* __restrict__ cursor) {
    __shared__ int s[256];
    const int t = threadIdx.x;
    const int base = blockIdx.x * SCAN_CHUNK + t * 4;
    int c0 = 0, c1 = 0, c2 = 0, c3 = 0;
    if (base + 0 < NN) c0 = counts[base + 0];
    if (base + 1 < NN) c1 = counts[base + 1];
    if (base + 2 < NN) c2 = counts[base + 2];
    if (base + 3 < NN) c3 = counts[base + 3];
    int tsum = c0 + c1 + c2 + c3;
    s[t] = tsum;
    __syncthreads();
    for (int off = 1; off < 256; off <<= 1) {
        int u = (t >= off) ? s[t - off] : 0;
        __syncthreads();
        s[t] += u;
        __syncthreads();
    }
    int run = blockOffs[blockIdx.x] + s[t] - tsum;   // exclusive prefix for this thread
    int p0 = run;
    int p1 = p0 + c0;
    int p2 = p1 + c1;
    int p3 = p2 + c2;
    if (base + 0 < NN) { row_ptr[base + 0] = p0; cursor[base + 0] = p0; }
    if (base + 1 < NN) { row_ptr[base + 1] = p1; cursor[base + 1] = p1; }
    if (base + 2 < NN) { row_ptr[base + 2] = p2; cursor[base + 2] = p2; }
    if (base + 3 < NN) { row_ptr[base + 3] = p3; cursor[base + 3] = p3; }
}

// ---------------------------------------------------------------------------
// CSR build step 3: scatter (col,val) pairs into row-sorted order
// ---------------------------------------------------------------------------
__global__ void __launch_bounds__(256)
scatter_kernel(const int*   __restrict__ rows,
               const int*   __restrict__ cols,
               const float* __restrict__ vals,
               int*         __restrict__ cursor,
               int2*        __restrict__ pairs) {
    int e = blockIdx.x * blockDim.x + threadIdx.x;
    if (e >= E_EDGES) return;
    int r = rows[e];
    int pos = atomicAdd(&cursor[r], 1);
    pairs[pos] = make_int2(cols[e], __float_as_int(vals[e]));
}

// ---------------------------------------------------------------------------
// Pull-mode SpMM: one wave per destination row, lane = dim.
// ---------------------------------------------------------------------------
template <bool FIRST>
__global__ void __launch_bounds__(256)
spmm_pull(const int*  __restrict__ row_ptr,
          const int2* __restrict__ pairs,
          const float* __restrict__ ut,
          const float* __restrict__ gt,
          const float* __restrict__ x,
          float*       __restrict__ y) {
    int row  = blockIdx.x * 4 + (threadIdx.x >> 6);   // 4 waves / block
    int lane = threadIdx.x & 63;
    if (row >= NN) return;
    int start = row_ptr[row];
    int end   = row_ptr[row + 1];

    auto loadx = [&](int c) -> float {
        if (FIRST) {
            return (c < NUM_USER) ? ut[(size_t)c * D + lane]
                                  : gt[(size_t)(c - NUM_USER) * D + lane];
        } else {
            return x[(size_t)c * D + lane];
        }
    };

    float acc = 0.f;
    int e = start;
    for (; e + 4 <= end; e += 4) {
        int2 p0 = pairs[e + 0];
        int2 p1 = pairs[e + 1];
        int2 p2 = pairs[e + 2];
        int2 p3 = pairs[e + 3];
        float x0 = loadx(p0.x);
        float x1 = loadx(p1.x);
        float x2 = loadx(p2.x);
        float x3 = loadx(p3.x);
        acc += __int_as_float(p0.y) * x0;
        acc += __int_as_float(p1.y) * x1;
        acc += __int_as_float(p2.y) * x2;
        acc += __int_as_float(p3.y) * x3;
    }
    for (; e < end; ++e) {
        int2 p = pairs[e];
        acc += __int_as_float(p.y) * loadx(p.x);
    }
    y[(size_t)row * D + lane] = acc;
}

// ---------------------------------------------------------------------------
// Output init: raw table gathers (outputs 3..5) and the level-0 contribution
// ---------------------------------------------------------------------------
__global__ void gather_init(const float* __restrict__ ut,
                            const float* __restrict__ gt,
                            const int*   __restrict__ ui,
                            const int*   __restrict__ pg,
                            const int*   __restrict__ ng,
                            float*       __restrict__ out) {
    int i = blockIdx.x * blockDim.x + threadIdx.x;    // B*D threads
    if (i >= B * D) return;
    int b = i >> 6, d = i & 63;
    float u = ut[(size_t)ui[b] * D + d];
    float p = gt[(size_t)pg[b] * D + d];
    float n = gt[(size_t)ng[b] * D + d];
    const int S = B * D;
    out[0 * S + i] = 0.25f * u;
    out[1 * S + i] = 0.25f * p;
    out[2 * S + i] = 0.25f * n;
    out[3 * S + i] = u;
    out[4 * S + i] = p;
    out[5 * S + i] = n;
}

// ---------------------------------------------------------------------------
// Per-level accumulation of 0.25 * emb_l at the gathered rows
// ---------------------------------------------------------------------------
__global__ void gather_acc(const float* __restrict__ emb,
                           const int*   __restrict__ ui,
                           const int*   __restrict__ pg,
                           const int*   __restrict__ ng,
                           float*       __restrict__ out) {
    int i = blockIdx.x * blockDim.x + threadIdx.x;    // B*D threads
    if (i >= B * D) return;
    int b = i >> 6, d = i & 63;
    const int S = B * D;
    out[0 * S + i] += 0.25f * emb[(size_t)ui[b] * D + d];
    out[1 * S + i] += 0.25f * emb[((size_t)NUM_USER + pg[b]) * D + d];
    out[2 * S + i] += 0.25f * emb[((size_t)NUM_USER + ng[b]) * D + d];
}

// ---------------------------------------------------------------------------
extern "C" void kernel_launch(void* const* d_in, const int* in_sizes, int n_in,
                              void* d_out, int out_size, void* d_ws, size_t ws_size,
                              hipStream_t stream) {
    const float* ut   = (const float*)d_in[0];
    const float* gt   = (const float*)d_in[1];
    const float* vals = (const float*)d_in[2];
    const int*   rows = (const int*)d_in[3];
    const int*   cols = (const int*)d_in[4];
    const int*   ui   = (const int*)d_in[5];
    const int*   pg   = (const int*)d_in[6];
    const int*   ng   = (const int*)d_in[7];
    float* out = (float*)d_out;

    // --- workspace layout ---
    char* ws = (char*)d_ws;
    float* emb_a   = (float*)ws;   ws += (size_t)NN * D * sizeof(float);   // 64 MB
    float* emb_b   = (float*)ws;   ws += (size_t)NN * D * sizeof(float);   // 64 MB
    int2*  pairs   = (int2*)ws;    ws += (size_t)E_EDGES * sizeof(int2);   // 32 MB
    int*   row_ptr = (int*)ws;     ws += (size_t)(NN + 1) * sizeof(int);
    int*   cursor  = (int*)ws;     ws += (size_t)NN * sizeof(int);
    int*   counts  = (int*)ws;     ws += (size_t)NN * sizeof(int);
    int*   blockSums = (int*)ws;   ws += (size_t)SCAN_BLOCKS * sizeof(int);
    int*   blockOffs = (int*)ws;   ws += (size_t)SCAN_BLOCKS * sizeof(int);

    // --- CSR build (once per call; reused for all 3 levels) ---
    hipMemsetAsync(counts, 0, (size_t)NN * sizeof(int), stream);
    hist_kernel<<<(E_EDGES + 255) / 256, 256, 0, stream>>>(rows, counts);
    scan_blocksums<<<SCAN_BLOCKS, 256, 0, stream>>>(counts, blockSums);
    scan_offsets<<<1, 256, 0, stream>>>(blockSums, blockOffs, row_ptr);
    scan_final<<<SCAN_BLOCKS, 256, 0, stream>>>(counts, blockOffs, row_ptr, cursor);
    scatter_kernel<<<(E_EDGES + 255) / 256, 256, 0, stream>>>(rows, cols, vals, cursor, pairs);

    // --- outputs 3..5 + level-0 contribution ---
    gather_init<<<(B * D + 255) / 256, 256, 0, stream>>>(ut, gt, ui, pg, ng, out);

    // --- 3 propagation levels, pull mode ---
    const int spmmBlocks = (NN + 3) / 4;   // 4 rows (waves) per 256-thread block
    spmm_pull<true><<<spmmBlocks, 256, 0, stream>>>(row_ptr, pairs, ut, gt, nullptr, emb_a);
    gather_acc<<<(B * D + 255) / 256, 256, 0, stream>>>(emb_a, ui, pg, ng, out);

    spmm_pull<false><<<spmmBlocks, 256, 0, stream>>>(row_ptr, pairs, ut, gt, emb_a, emb_b);
    gather_acc<<<(B * D + 255) / 256, 256, 0, stream>>>(emb_b, ui, pg, ng, out);

    spmm_pull<false><<<spmmBlocks, 256, 0, stream>>>(row_ptr, pairs, ut, gt, emb_b, emb_a);
    gather_acc<<<(B * D + 255) / 256, 256, 0, stream>>>(emb_a, ui, pg, ng, out);
}